// Round 1
// baseline (180.865 us; speedup 1.0000x reference)
//
#include <hip/hip_runtime.h>
#include <math.h>

// Problem dims (fixed per reference)
#define B_DIM 32
#define C_DIM 256
#define K_DIM 32
#define N_DIM 4096   // 64*64

// ws layout (float offsets)
//   [0,      8192)  cw_t [C][K]   (transposed codewords)
//   [8192,   8224)  c2   [K]
//   [8224,  16416)  S    [B][C]   (zeroed each call)
//   [16416, 17440)  a_sum[B][K]   (zeroed each call)
#define WS_CWT   0
#define WS_C2    8192
#define WS_S     8224
#define WS_ASUM  16416

__global__ void ce_prep_kernel(const float* __restrict__ cw, float* __restrict__ ws) {
    float* cw_t = ws + WS_CWT;
    float* c2   = ws + WS_C2;
    int c = threadIdx.x;  // 256 threads
    #pragma unroll
    for (int k = 0; k < K_DIM; ++k)
        cw_t[c * K_DIM + k] = cw[k * C_DIM + c];
    if (c < K_DIM) {
        int k = c;
        float s = 0.f;
        for (int cc = 0; cc < C_DIM; ++cc) {
            float v = cw[k * C_DIM + cc];
            s = fmaf(v, v, s);
        }
        c2[k] = s;
    }
}

__global__ __launch_bounds__(256, 2)
void ce_main_kernel(const float* __restrict__ x,
                    const float* __restrict__ scale,
                    const float* __restrict__ cw_t,
                    const float* __restrict__ c2,
                    float* __restrict__ Sg,
                    float* __restrict__ a_sum_g) {
    __shared__ float lds_S[C_DIM];

    const int tid  = threadIdx.x;            // 0..255
    const int b    = blockIdx.y;             // 0..31
    const int n    = blockIdx.x * 256 + tid; // 0..4095
    const int lane = tid & 63;

    lds_S[tid] = 0.f;
    __syncthreads();

    const float* xb = x + (size_t)b * ((size_t)C_DIM * N_DIM) + n;

    float dot[K_DIM];
    #pragma unroll
    for (int k = 0; k < K_DIM; ++k) dot[k] = 0.f;
    float f2 = 0.f;

    #pragma unroll 4
    for (int c = 0; c < C_DIM; ++c) {
        float f = xb[(size_t)c * N_DIM];
        f2 = fmaf(f, f, f2);
        const float* cwc = cw_t + c * K_DIM;  // uniform address -> scalar loads
        #pragma unroll
        for (int k = 0; k < K_DIM; ++k)
            dot[k] = fmaf(f, cwc[k], dot[k]);
        // wave-sum of f for S[b,c]
        float s = f;
        s += __shfl_xor(s, 1);
        s += __shfl_xor(s, 2);
        s += __shfl_xor(s, 4);
        s += __shfl_xor(s, 8);
        s += __shfl_xor(s, 16);
        s += __shfl_xor(s, 32);
        if (lane == 0) atomicAdd(&lds_S[c], s);
    }

    // per-thread softmax over k (numerically stable)
    float a[K_DIM];
    float m = -1e30f;
    #pragma unroll
    for (int k = 0; k < K_DIM; ++k) {
        float d2 = f2 + c2[k] - 2.f * dot[k];
        float dist = sqrtf(fmaxf(d2, 0.f));
        float L = -dist * scale[k];
        a[k] = L;
        m = fmaxf(m, L);
    }
    float sum = 0.f;
    #pragma unroll
    for (int k = 0; k < K_DIM; ++k) {
        float e = __expf(a[k] - m);
        a[k] = e;
        sum += e;
    }
    float inv = 1.f / sum;

    // wave-reduce each a[k]; lane k keeps the wave total
    float mine = 0.f;
    #pragma unroll
    for (int k = 0; k < K_DIM; ++k) {
        float v = a[k] * inv;
        v += __shfl_xor(v, 1);
        v += __shfl_xor(v, 2);
        v += __shfl_xor(v, 4);
        v += __shfl_xor(v, 8);
        v += __shfl_xor(v, 16);
        v += __shfl_xor(v, 32);
        if (lane == k) mine = v;
    }
    if (lane < K_DIM)
        atomicAdd(&a_sum_g[b * K_DIM + lane], mine);

    __syncthreads();
    atomicAdd(&Sg[b * C_DIM + tid], lds_S[tid]);
}

__global__ void ce_final_kernel(float* __restrict__ out,
                                const float* __restrict__ cw_t,
                                const float* __restrict__ Sg,
                                const float* __restrict__ a_sum) {
    const int b = blockIdx.x;
    const int c = threadIdx.x;
    float acc = 0.f;
    #pragma unroll
    for (int k = 0; k < K_DIM; ++k)
        acc = fmaf(a_sum[b * K_DIM + k], cw_t[c * K_DIM + k], acc);
    out[b * C_DIM + c] = (Sg[b * C_DIM + c] - acc) * (1.0f / (float)K_DIM);
}

extern "C" void kernel_launch(void* const* d_in, const int* in_sizes, int n_in,
                              void* d_out, int out_size, void* d_ws, size_t ws_size,
                              hipStream_t stream) {
    const float* x     = (const float*)d_in[0];
    const float* cw    = (const float*)d_in[1];
    const float* scale = (const float*)d_in[2];
    float* out = (float*)d_out;
    float* ws  = (float*)d_ws;

    // zero S and a_sum accumulators (every call; ws is not re-poisoned but
    // we must not rely on leftover state)
    hipMemsetAsync((char*)d_ws + WS_S * sizeof(float), 0,
                   (size_t)(C_DIM * B_DIM + B_DIM * K_DIM) * sizeof(float), stream);

    ce_prep_kernel<<<1, 256, 0, stream>>>(cw, ws);

    dim3 grid(N_DIM / 256, B_DIM);
    ce_main_kernel<<<grid, 256, 0, stream>>>(x, scale,
                                             ws + WS_CWT, ws + WS_C2,
                                             ws + WS_S, ws + WS_ASUM);

    ce_final_kernel<<<B_DIM, 256, 0, stream>>>(out, ws + WS_CWT, ws + WS_S, ws + WS_ASUM);
}

// Round 2
// 96.061 us; speedup vs baseline: 1.8828x; 1.8828x over previous
//
#include <hip/hip_runtime.h>
#include <math.h>

// Problem dims (fixed per reference)
#define B_DIM 32
#define C_DIM 256
#define K_DIM 32
#define N_DIM 4096   // 64*64
#define TC    32     // channels per LDS tile in main kernel

// ws layout (float offsets)
//   [0,      8192)  cw_t [C][K]   (transposed codewords)
//   [8192,   8224)  c2   [K]
//   [8224,  16416)  S    [B][C]   (written by sum kernel, single writer)
//   [16416, 17440)  a_sum[B][K]   (zeroed each call, atomic accum)
#define WS_CWT   0
#define WS_C2    8192
#define WS_S     8224
#define WS_ASUM  16416

__global__ void ce_prep_kernel(const float* __restrict__ cw, float* __restrict__ ws) {
    float* cw_t = ws + WS_CWT;
    float* c2   = ws + WS_C2;
    int c = threadIdx.x;  // 256 threads
    #pragma unroll
    for (int k = 0; k < K_DIM; ++k)
        cw_t[c * K_DIM + k] = cw[k * C_DIM + c];
    if (c < K_DIM) {
        int k = c;
        float s = 0.f;
        for (int cc = 0; cc < C_DIM; ++cc) {
            float v = cw[k * C_DIM + cc];
            s = fmaf(v, v, s);
        }
        c2[k] = s;
    }
}

// S[b,c] = sum_n x[b,c,n] : one wave per (b,c) row, float4 loads, no atomics
__global__ __launch_bounds__(256)
void ce_sum_kernel(const float* __restrict__ x, float* __restrict__ Sg) {
    const int row  = blockIdx.x * 4 + (threadIdx.x >> 6);  // b*C + c
    const int lane = threadIdx.x & 63;
    const float4* p = (const float4*)(x + (size_t)row * N_DIM);
    float s = 0.f;
    #pragma unroll
    for (int i = 0; i < 16; ++i) {
        float4 v = p[i * 64 + lane];
        s += (v.x + v.y) + (v.z + v.w);
    }
    s += __shfl_xor(s, 1);
    s += __shfl_xor(s, 2);
    s += __shfl_xor(s, 4);
    s += __shfl_xor(s, 8);
    s += __shfl_xor(s, 16);
    s += __shfl_xor(s, 32);
    if (lane == 0) Sg[row] = s;
}

__device__ __forceinline__ void stage_tile(const float* __restrict__ xb,
                                           float* ldsbase, int c0,
                                           int wave, int lane) {
    // each wave DMAs 8 rows of [TC][256]; LDS dst is wave-uniform base,
    // HW adds lane*16; global src is per-lane.
    #pragma unroll
    for (int r = 0; r < 8; ++r) {
        int row = wave * 8 + r;
        const float* src = xb + (size_t)(c0 + row) * N_DIM + (lane << 2);
        __builtin_amdgcn_global_load_lds(
            (const __attribute__((address_space(1))) void*)src,
            (__attribute__((address_space(3))) void*)(ldsbase + row * 256),
            16, 0, 0);
    }
}

__global__ __launch_bounds__(256, 2)
void ce_main_kernel(const float* __restrict__ x,
                    const float* __restrict__ scale,
                    const float* __restrict__ cw_t,
                    const float* __restrict__ c2,
                    float* __restrict__ a_sum_g) {
    __shared__ float tile[2][TC * 256];

    const int tid  = threadIdx.x;            // 0..255  (= local n)
    const int b    = blockIdx.y;             // 0..31
    const int wave = tid >> 6;
    const int lane = tid & 63;

    const float* xb = x + (size_t)b * ((size_t)C_DIM * N_DIM) + blockIdx.x * 256;

    float dot[K_DIM];
    #pragma unroll
    for (int k = 0; k < K_DIM; ++k) dot[k] = 0.f;
    float f2 = 0.f;

    stage_tile(xb, &tile[0][0], 0, wave, lane);
    __syncthreads();

    for (int t = 0; t < C_DIM / TC; ++t) {
        const int cur = t & 1;
        if (t < C_DIM / TC - 1)
            stage_tile(xb, &tile[cur ^ 1][0], (t + 1) * TC, wave, lane);

        const float* cwb = cw_t + t * TC * K_DIM;
        #pragma unroll 4
        for (int cc = 0; cc < TC; ++cc) {
            float f = tile[cur][cc * 256 + tid];
            f2 = fmaf(f, f, f2);
            const float* cwc = cwb + cc * K_DIM;  // uniform -> scalar loads
            #pragma unroll
            for (int k = 0; k < K_DIM; ++k)
                dot[k] = fmaf(f, cwc[k], dot[k]);
        }
        __syncthreads();
    }

    // per-thread softmax over k (numerically stable)
    float a[K_DIM];
    float m = -1e30f;
    #pragma unroll
    for (int k = 0; k < K_DIM; ++k) {
        float d2 = f2 + c2[k] - 2.f * dot[k];
        float dist = sqrtf(fmaxf(d2, 0.f));
        float L = -dist * scale[k];
        a[k] = L;
        m = fmaxf(m, L);
    }
    float sum = 0.f;
    #pragma unroll
    for (int k = 0; k < K_DIM; ++k) {
        float e = __expf(a[k] - m);
        a[k] = e;
        sum += e;
    }
    float inv = 1.f / sum;

    // wave-reduce each a[k]; lane k keeps the wave total
    float mine = 0.f;
    #pragma unroll
    for (int k = 0; k < K_DIM; ++k) {
        float v = a[k] * inv;
        v += __shfl_xor(v, 1);
        v += __shfl_xor(v, 2);
        v += __shfl_xor(v, 4);
        v += __shfl_xor(v, 8);
        v += __shfl_xor(v, 16);
        v += __shfl_xor(v, 32);
        if (lane == k) mine = v;
    }
    if (lane < K_DIM)
        atomicAdd(&a_sum_g[b * K_DIM + lane], mine);
}

__global__ void ce_final_kernel(float* __restrict__ out,
                                const float* __restrict__ cw_t,
                                const float* __restrict__ Sg,
                                const float* __restrict__ a_sum) {
    const int b = blockIdx.x;
    const int c = threadIdx.x;
    float acc = 0.f;
    #pragma unroll
    for (int k = 0; k < K_DIM; ++k)
        acc = fmaf(a_sum[b * K_DIM + k], cw_t[c * K_DIM + k], acc);
    out[b * C_DIM + c] = (Sg[b * C_DIM + c] - acc) * (1.0f / (float)K_DIM);
}

extern "C" void kernel_launch(void* const* d_in, const int* in_sizes, int n_in,
                              void* d_out, int out_size, void* d_ws, size_t ws_size,
                              hipStream_t stream) {
    const float* x     = (const float*)d_in[0];
    const float* cw    = (const float*)d_in[1];
    const float* scale = (const float*)d_in[2];
    float* out = (float*)d_out;
    float* ws  = (float*)d_ws;

    // zero the a_sum atomic accumulator every call
    hipMemsetAsync((char*)d_ws + WS_ASUM * sizeof(float), 0,
                   (size_t)(B_DIM * K_DIM) * sizeof(float), stream);

    ce_prep_kernel<<<1, 256, 0, stream>>>(cw, ws);

    ce_sum_kernel<<<(B_DIM * C_DIM) / 4, 256, 0, stream>>>(x, ws + WS_S);

    dim3 grid(N_DIM / 256, B_DIM);
    ce_main_kernel<<<grid, 256, 0, stream>>>(x, scale,
                                             ws + WS_CWT, ws + WS_C2,
                                             ws + WS_ASUM);

    ce_final_kernel<<<B_DIM, 256, 0, stream>>>(out, ws + WS_CWT, ws + WS_S, ws + WS_ASUM);
}

// Round 3
// 86.976 us; speedup vs baseline: 2.0795x; 1.1045x over previous
//
#include <hip/hip_runtime.h>
#include <math.h>

// Problem dims (fixed per reference)
#define B_DIM 32
#define C_DIM 256
#define K_DIM 32
#define N_DIM 4096   // 64*64
#define TC    32     // channels per LDS tile in main kernel
#define NSLICE 16    // N_DIM / 256

// ws layout (float offsets) — every slot fully overwritten each call,
// no zeroing needed, no atomics anywhere.
//   [0,      8192)   cw_t  [C][K]        (transposed codewords)
//   [8192,   8224)   c2    [K]
//   [8224, 139296)   Spart [B][16][C]    (per-slice partial row sums)
//   [139296,155680)  a_part[B][16][K]    (per-slice partial a sums)
#define WS_CWT   0
#define WS_C2    8192
#define WS_SPART 8224
#define WS_APART 139296

__global__ void ce_prep_kernel(const float* __restrict__ cw, float* __restrict__ ws) {
    float* cw_t = ws + WS_CWT;
    float* c2   = ws + WS_C2;
    int c = threadIdx.x;  // 256 threads
    #pragma unroll
    for (int k = 0; k < K_DIM; ++k)
        cw_t[c * K_DIM + k] = cw[k * C_DIM + c];
    if (c < K_DIM) {
        int k = c;
        float s = 0.f;
        for (int cc = 0; cc < C_DIM; ++cc) {
            float v = cw[k * C_DIM + cc];
            s = fmaf(v, v, s);
        }
        c2[k] = s;
    }
}

__device__ __forceinline__ void stage_tile(const float* __restrict__ xb,
                                           float* ldsbase, int c0,
                                           int wave, int lane) {
    // each wave DMAs 8 rows of [TC][256]; LDS dst is wave-uniform base,
    // HW adds lane*16; global src is per-lane.
    #pragma unroll
    for (int r = 0; r < 8; ++r) {
        int row = wave * 8 + r;
        const float* src = xb + (size_t)(c0 + row) * N_DIM + (lane << 2);
        __builtin_amdgcn_global_load_lds(
            (const __attribute__((address_space(1))) void*)src,
            (__attribute__((address_space(3))) void*)(ldsbase + row * 256),
            16, 0, 0);
    }
}

__global__ __launch_bounds__(256, 2)
void ce_main_kernel(const float* __restrict__ x,
                    const float* __restrict__ scale,
                    const float* __restrict__ cw_t,
                    const float* __restrict__ c2,
                    float* __restrict__ Spart,
                    float* __restrict__ a_part) {
    __shared__ float tile[2][TC * 256];
    __shared__ float awave[4][K_DIM];

    const int tid  = threadIdx.x;            // 0..255  (= local n)
    const int s    = blockIdx.x;             // 0..15 slice
    const int b    = blockIdx.y;             // 0..31
    const int wave = tid >> 6;
    const int lane = tid & 63;

    const float* xb = x + (size_t)b * ((size_t)C_DIM * N_DIM) + s * 256;
    float* Sp = Spart + ((size_t)b * NSLICE + s) * C_DIM;

    float dot[K_DIM];
    #pragma unroll
    for (int k = 0; k < K_DIM; ++k) dot[k] = 0.f;
    float f2 = 0.f;

    stage_tile(xb, &tile[0][0], 0, wave, lane);
    __syncthreads();

    for (int t = 0; t < C_DIM / TC; ++t) {
        const int cur = t & 1;
        if (t < C_DIM / TC - 1)
            stage_tile(xb, &tile[cur ^ 1][0], (t + 1) * TC, wave, lane);

        const float* cwb = cw_t + t * TC * K_DIM;
        #pragma unroll 4
        for (int cc = 0; cc < TC; ++cc) {
            float f = tile[cur][cc * 256 + tid];
            f2 = fmaf(f, f, f2);
            const float* cwc = cwb + cc * K_DIM;  // uniform -> scalar loads
            #pragma unroll
            for (int k = 0; k < K_DIM; ++k)
                dot[k] = fmaf(f, cwc[k], dot[k]);
        }

        // per-row sums of this tile (for S[b,c]); wave w owns rows w*8..w*8+7
        #pragma unroll
        for (int r = 0; r < 8; ++r) {
            int row = wave * 8 + r;
            const float4* rowp = (const float4*)&tile[cur][row * 256];
            float4 v = rowp[lane];
            float rs = (v.x + v.y) + (v.z + v.w);
            rs += __shfl_xor(rs, 1);
            rs += __shfl_xor(rs, 2);
            rs += __shfl_xor(rs, 4);
            rs += __shfl_xor(rs, 8);
            rs += __shfl_xor(rs, 16);
            rs += __shfl_xor(rs, 32);
            if (lane == 0) Sp[t * TC + row] = rs;
        }

        __syncthreads();
    }

    // per-thread softmax over k (numerically stable)
    float a[K_DIM];
    float m = -1e30f;
    #pragma unroll
    for (int k = 0; k < K_DIM; ++k) {
        float d2 = f2 + c2[k] - 2.f * dot[k];
        float dist = sqrtf(fmaxf(d2, 0.f));
        float L = -dist * scale[k];
        a[k] = L;
        m = fmaxf(m, L);
    }
    float sum = 0.f;
    #pragma unroll
    for (int k = 0; k < K_DIM; ++k) {
        float e = __expf(a[k] - m);
        a[k] = e;
        sum += e;
    }
    float inv = 1.f / sum;

    // wave-reduce each a[k]; lane k keeps the wave total
    float mine = 0.f;
    #pragma unroll
    for (int k = 0; k < K_DIM; ++k) {
        float v = a[k] * inv;
        v += __shfl_xor(v, 1);
        v += __shfl_xor(v, 2);
        v += __shfl_xor(v, 4);
        v += __shfl_xor(v, 8);
        v += __shfl_xor(v, 16);
        v += __shfl_xor(v, 32);
        if (lane == k) mine = v;
    }
    if (lane < K_DIM) awave[wave][lane] = mine;
    __syncthreads();
    if (tid < K_DIM) {
        float t0 = awave[0][tid] + awave[1][tid];
        float t1 = awave[2][tid] + awave[3][tid];
        a_part[((size_t)b * NSLICE + s) * K_DIM + tid] = t0 + t1;
    }
}

__global__ void ce_final_kernel(float* __restrict__ out,
                                const float* __restrict__ cw_t,
                                const float* __restrict__ Spart,
                                const float* __restrict__ a_part) {
    __shared__ float asum_l[K_DIM];
    const int b = blockIdx.x;
    const int c = threadIdx.x;

    if (c < K_DIM) {
        float a = 0.f;
        #pragma unroll
        for (int s = 0; s < NSLICE; ++s)
            a += a_part[((size_t)b * NSLICE + s) * K_DIM + c];
        asum_l[c] = a;
    }
    __syncthreads();

    float S = 0.f;
    #pragma unroll
    for (int s = 0; s < NSLICE; ++s)
        S += Spart[((size_t)b * NSLICE + s) * C_DIM + c];

    float acc = 0.f;
    #pragma unroll
    for (int k = 0; k < K_DIM; ++k)
        acc = fmaf(asum_l[k], cw_t[c * K_DIM + k], acc);
    out[b * C_DIM + c] = (S - acc) * (1.0f / (float)K_DIM);
}

extern "C" void kernel_launch(void* const* d_in, const int* in_sizes, int n_in,
                              void* d_out, int out_size, void* d_ws, size_t ws_size,
                              hipStream_t stream) {
    const float* x     = (const float*)d_in[0];
    const float* cw    = (const float*)d_in[1];
    const float* scale = (const float*)d_in[2];
    float* out = (float*)d_out;
    float* ws  = (float*)d_ws;

    ce_prep_kernel<<<1, 256, 0, stream>>>(cw, ws);

    dim3 grid(NSLICE, B_DIM);
    ce_main_kernel<<<grid, 256, 0, stream>>>(x, scale,
                                             ws + WS_CWT, ws + WS_C2,
                                             ws + WS_SPART, ws + WS_APART);

    ce_final_kernel<<<B_DIM, 256, 0, stream>>>(out, ws + WS_CWT,
                                               ws + WS_SPART, ws + WS_APART);
}